// Round 12
// baseline (613.847 us; speedup 1.0000x reference)
//
#include <hip/hip_runtime.h>
#include <math.h>

#define NTOK 32768      // B*T
#define DD 256
#define MM 400
#define BB 64
#define TT 512

// workspace layout (bytes)
#define WS_PH     0          // float [2][64][400]
#define WS_ROWCNT 204800     // int   [2][64][400]
#define WS_ERR    409600     // float [4][64]  slotted error sums
#define WS_ZERO_BYTES 410624
#define WS_IDX    410624     // int   [2][32768]
#define WS_ESQ    672768     // float [400]
#define WS_LG     674368     // float [2][64][400]
#define WS_SC     879168     // float [64][64]
#define WS_MODE   895552     // int   [128]
#define WS_EH     896064     // ushort [400][256] bf16 hi  (204800 B)
#define WS_EL     1100864    // ushort [400][256] bf16 lo  (204800 B)

typedef __attribute__((ext_vector_type(8))) short bf16x8;   // 8 bf16 = 4 VGPR
typedef __attribute__((ext_vector_type(4))) float f32x4;

// ---------------------------------------------------------------- e_sq + bf16 split of emb
__global__ void k_esq(const float* __restrict__ emb, float* __restrict__ esq,
                      unsigned short* __restrict__ eh, unsigned short* __restrict__ el) {
    int m = blockIdx.x, lane = threadIdx.x;
    float s = 0.f;
    for (int k = lane; k < DD; k += 64) {
        float e = emb[m * DD + k];
        s += e * e;
        unsigned u = __float_as_uint(e);
        unsigned short hu = (unsigned short)((u + 0x7FFFu + ((u >> 16) & 1u)) >> 16);
        float hf = __uint_as_float((unsigned)hu << 16);
        float lf = e - hf;
        unsigned ul = __float_as_uint(lf);
        unsigned short lu = (unsigned short)((ul + 0x7FFFu + ((ul >> 16) & 1u)) >> 16);
        eh[m * DD + k] = hu;
        el[m * DD + k] = lu;
    }
    #pragma unroll
    for (int off = 1; off < 64; off <<= 1) s += __shfl_xor(s, off, 64);
    if (lane == 0) esq[m] = s;
}

// ---------------------------------------------------------------- main fused kernel (MFMA)
// Ledger:
// R1  (VERIFIED 594.9->569.8): global_load_lds e-staging. k1=368us @16 waves/CU.
// R5  (NEUTRAL): e dbuf -> stage drain not the stall.
// R7/R8 (REGRESSION): x->LDS; VGPR>128 -> 8-wave tier (HW granule 64/128/256).
// R10 (REGRESSION 604): TOK=16; VGPR 100 is the SAME 16-wave tier as 124 ->
//     no occupancy gain, 2x LDS/staging overhead. fp32-VALU path is stuck
//     at ~370us: per-SIMD issue 28%, latency-bound, no reachable tier above.
// R11 (this): bf16 split-precision MFMA. X=Xh+Xl, E=Eh+El (bf16);
//     dot = Xh*Eh + Xh*El + Xl*Eh (drop Xl*El ~1e-6 abs). Layout safety:
//     A and B fragments are loaded with the SAME (lane&15 = row/col,
//     lane>>4 = k-group, elem j) convention as contiguous 16B k-slices;
//     MFMA contraction is slot-symmetric so any internal k-map gives the
//     exact sum. C/D layout = guide-verified col=lane&15, row=4*(lane>>4)+reg.
//     Per wave: 16 tokens; X-frags in regs (64 VGPR); E-frags read DIRECT
//     from global (embH/L = 400KB, L2-resident) -> NO barriers in main loop.
//     Softmax with per-token offset sqrt(xs) (exp arg in [-0.1,0.05], no max
//     pass). Two passes over 25 code-tiles: A = argmin + sum-exp, B =
//     recompute + pH accumulation. xs/esq exact fp32 (argmin xs-independent).
__launch_bounds__(256)
__global__ void k1_mfma(const float* __restrict__ a, const float* __restrict__ v,
                        const unsigned short* __restrict__ eh,
                        const unsigned short* __restrict__ el,
                        const float* __restrict__ esq_g,
                        float* __restrict__ pH_g,
                        int* __restrict__ rowcnt, int* __restrict__ idxws) {
    __shared__ float pH_w[4 * MM];     // 6.4 KB
    __shared__ float xs_sh[4][16];

    const int tid = threadIdx.x;
    const int l   = tid & 63;
    const int wv  = tid >> 6;
    const int bx  = blockIdx.x;
    const int mod = bx >> 9;           // 1024 blocks: 512 per modality
    const int seg = bx & 511;
    const int blk0 = seg * 64;         // 64 tokens per block
    const int b    = seg >> 3;         // 512-token rows
    const int tok0 = blk0 + wv * 16;   // 16 tokens per wave
    const float* xg = (mod == 0) ? a : v;

    const int r = l & 15;              // A-row (token) / B-col (code) index
    const int h = l >> 4;              // k-group
    const int myTok = tok0 + r;

    // ---- prologue: load this lane's X k-slices, split to bf16 h/l, partial xs
    bf16x8 Xh[8], Xl[8];
    float xs_part = 0.f;
    #pragma unroll
    for (int s = 0; s < 8; ++s) {
        const float* p = xg + (size_t)myTok * DD + 32 * s + 8 * h;
        float4 f0 = *(const float4*)(p);
        float4 f1 = *(const float4*)(p + 4);
        bf16x8 th, tl;
        float e;
#define CVT(J, EV) { e = (EV); xs_part += e * e; \
        unsigned uu = __float_as_uint(e); \
        unsigned short hu = (unsigned short)((uu + 0x7FFFu + ((uu >> 16) & 1u)) >> 16); \
        float hf = __uint_as_float((unsigned)hu << 16); \
        float lf = e - hf; \
        unsigned ul = __float_as_uint(lf); \
        unsigned short lu = (unsigned short)((ul + 0x7FFFu + ((ul >> 16) & 1u)) >> 16); \
        th[J] = (short)hu; tl[J] = (short)lu; }
        CVT(0, f0.x) CVT(1, f0.y) CVT(2, f0.z) CVT(3, f0.w)
        CVT(4, f1.x) CVT(5, f1.y) CVT(6, f1.z) CVT(7, f1.w)
#undef CVT
        Xh[s] = th; Xl[s] = tl;
    }
    // xs for token r: combine the 4 h-groups (lanes r, r+16, r+32, r+48)
    xs_part += __shfl_xor(xs_part, 16, 64);
    xs_part += __shfl_xor(xs_part, 32, 64);
    if (h == 0) xs_sh[wv][r] = xs_part;
    __syncthreads();
    // epilogue tokens for this lane: tt = tok0 + 4*h + q  (C/D row = 4*(l>>4)+q)
    float xs4[4], sqx4[4];
    #pragma unroll
    for (int q = 0; q < 4; ++q) {
        xs4[q]  = xs_sh[wv][4 * h + q];
        sqx4[q] = sqrtf(xs4[q]);
    }

    // shared 8-slab MFMA tile body (A/B same-k-convention; see header)
#define TILE_DOT(ACC, EHP, ELP) { \
        _Pragma("unroll") \
        for (int s = 0; s < 8; ++s) { \
            bf16x8 Eh_ = *(const bf16x8*)((EHP) + 32 * s); \
            bf16x8 El_ = *(const bf16x8*)((ELP) + 32 * s); \
            ACC = __builtin_amdgcn_mfma_f32_16x16x32_bf16(Xh[s], Eh_, ACC, 0, 0, 0); \
            ACC = __builtin_amdgcn_mfma_f32_16x16x32_bf16(Xh[s], El_, ACC, 0, 0, 0); \
            ACC = __builtin_amdgcn_mfma_f32_16x16x32_bf16(Xl[s], Eh_, ACC, 0, 0, 0); \
        } }

    // ---- pass A: argmin + sum-exp (online, offset = sqrt(xs))
    float mind[4] = {1e30f, 1e30f, 1e30f, 1e30f};
    int   marg[4] = {0, 0, 0, 0};
    float se[4]   = {0.f, 0.f, 0.f, 0.f};
    for (int ct = 0; ct < 25; ++ct) {
        const unsigned short* ehp = eh + ((size_t)(ct * 16 + r)) * DD + 8 * h;
        const unsigned short* elp = el + ((size_t)(ct * 16 + r)) * DD + 8 * h;
        f32x4 acc = {0.f, 0.f, 0.f, 0.f};
        TILE_DOT(acc, ehp, elp)
        const int c = ct * 16 + r;
        const float ec = esq_g[c];
        #pragma unroll
        for (int q = 0; q < 4; ++q) {
            float dist = fmaf(-2.f, acc[q], xs4[q] + ec);
            float z = sqx4[q] - sqrtf(fmaxf(dist, 0.f));
            se[q] += __expf(z);
            if (dist < mind[q]) { mind[q] = dist; marg[q] = c; }
        }
    }
    // reduce across the 16 lanes of this h-group (they hold different codes)
    #pragma unroll
    for (int q = 0; q < 4; ++q) {
        float bd = mind[q]; int bi = marg[q]; float s_ = se[q];
        #pragma unroll
        for (int off = 1; off < 16; off <<= 1) {
            float od = __shfl_xor(bd, off, 64);
            int   oi = __shfl_xor(bi, off, 64);
            s_ += __shfl_xor(s_, off, 64);
            if (od < bd || (od == bd && oi < bi)) { bd = od; bi = oi; }
        }
        se[q] = 1.f / s_;           // keep inverse for pass B
        if (r == 0) {
            int n = tok0 + 4 * h + q;
            idxws[mod * NTOK + n] = bi;
            atomicAdd(&rowcnt[(mod * BB + b) * MM + bi], 1);
        }
    }

    // ---- pass B: recompute dots, accumulate pH (per-wave row of pH_w)
    for (int ct = 0; ct < 25; ++ct) {
        const unsigned short* ehp = eh + ((size_t)(ct * 16 + r)) * DD + 8 * h;
        const unsigned short* elp = el + ((size_t)(ct * 16 + r)) * DD + 8 * h;
        f32x4 acc = {0.f, 0.f, 0.f, 0.f};
        TILE_DOT(acc, ehp, elp)
        const int c = ct * 16 + r;
        const float ec = esq_g[c];
        float val = 0.f;
        #pragma unroll
        for (int q = 0; q < 4; ++q) {
            float dist = fmaf(-2.f, acc[q], xs4[q] + ec);
            float z = sqx4[q] - sqrtf(fmaxf(dist, 0.f));
            val = fmaf(__expf(z), se[q], val);
        }
        // sum over the wave's 16 tokens (4 per lane x 4 h-groups)
        val += __shfl_xor(val, 16, 64);
        val += __shfl_xor(val, 32, 64);
        if (h == 0) pH_w[wv * MM + c] = val;
    }
#undef TILE_DOT

    __syncthreads();
    for (int m = tid; m < MM; m += 256) {
        float s = pH_w[m] + pH_w[MM + m] + pH_w[2 * MM + m] + pH_w[3 * MM + m];
        atomicAdd(&pH_g[(size_t)(mod * BB + b) * MM + m], s);
    }
}

// ---------------------------------------------------------------- quantized outputs + error sums
__global__ void k_err(const float* __restrict__ a, const float* __restrict__ v,
                      const float* __restrict__ emb, const int* __restrict__ idxws,
                      float* __restrict__ out, float* __restrict__ err) {
    const int mod = blockIdx.y;
    const int tid = threadIdx.x;
    const int gid = blockIdx.x * 256 + tid;
    const int n  = gid >> 6;
    const int d4 = (gid & 63) << 2;
    const int ia = idxws[n];
    const int iv = idxws[NTOK + n];
    const int own = (mod == 0) ? ia : iv;
    const int oth = (mod == 0) ? iv : ia;
    const float* x = (mod == 0) ? a : v;

    float4 xv = *(const float4*)(x + (size_t)n * DD + d4);
    float4 qo = *(const float4*)(emb + (size_t)own * DD + d4);
    float4 qc = *(const float4*)(emb + (size_t)oth * DD + d4);
    *(float4*)(out + (size_t)mod * NTOK * DD + (size_t)n * DD + d4) = qo;

    float eo, ec;
    { float dx = xv.x - qo.x, dy = xv.y - qo.y, dz = xv.z - qo.z, dw = xv.w - qo.w;
      eo = dx * dx + dy * dy + dz * dz + dw * dw; }
    { float dx = xv.x - qc.x, dy = xv.y - qc.y, dz = xv.z - qc.z, dw = xv.w - qc.w;
      ec = dx * dx + dy * dy + dz * dz + dw * dw; }

    #pragma unroll
    for (int off = 1; off < 64; off <<= 1) {
        eo += __shfl_xor(eo, off, 64);
        ec += __shfl_xor(ec, off, 64);
    }
    __shared__ float ro[4], rc[4];
    if ((tid & 63) == 0) { ro[tid >> 6] = eo; rc[tid >> 6] = ec; }
    __syncthreads();
    if (tid == 0) {
        int slot = blockIdx.x & 63;    // 64-way slotted: contention /64
        atomicAdd(&err[(mod * 2 + 0) * 64 + slot], ro[0] + ro[1] + ro[2] + ro[3]);
        atomicAdd(&err[(mod * 2 + 1) * 64 + slot], rc[0] + rc[1] + rc[2] + rc[3]);
    }
}

// ---------------------------------------------------------------- normalize pH, logs
__global__ void k2_norm(float* __restrict__ pH, float* __restrict__ Lg) {
    int i = blockIdx.x * 256 + threadIdx.x;
    if (i < 2 * BB * MM) {
        float p = pH[i] * (1.f / TT);
        pH[i] = p;
        Lg[i] = logf(p + 1e-10f);
    }
}

// ---------------------------------------------------------------- per-row mode
__global__ void k3_mode(const int* __restrict__ rowcnt, int* __restrict__ modes) {
    int r = blockIdx.x, lane = threadIdx.x;
    const int* cnt = rowcnt + r * MM;
    int bc = -1, bi = 0x7fffffff;
    for (int m = lane; m < MM; m += 64) {
        int c = cnt[m];
        if (c > bc) { bc = c; bi = m; }
    }
    #pragma unroll
    for (int off = 1; off < 64; off <<= 1) {
        int oc = __shfl_xor(bc, off, 64);
        int oi = __shfl_xor(bi, off, 64);
        if (oc > bc || (oc == bc && oi < bi)) { bc = oc; bi = oi; }
    }
    if (lane == 0) modes[r] = bi;
}

// ---------------------------------------------------------------- Scode (64x64, K=400, x2 terms)
__global__ void k4_scode(const float* __restrict__ pH, const float* __restrict__ Lg,
                         float* __restrict__ Sc) {
    int i = blockIdx.x;
    int tid = threadIdx.x, lane = tid & 63, wv = tid >> 6;
    const float* aPH = pH + (size_t)i * MM;
    const float* vPH = pH + (size_t)(BB + i) * MM;
    for (int jj = 0; jj < 16; ++jj) {
        int j = wv * 16 + jj;
        const float* Lv = Lg + (size_t)(BB + j) * MM;
        const float* La = Lg + (size_t)j * MM;
        float s = 0.f;
        for (int m = lane; m < MM; m += 64)
            s += aPH[m] * Lv[m] + vPH[m] * La[m];
        #pragma unroll
        for (int off = 1; off < 64; off <<= 1) s += __shfl_xor(s, off, 64);
        if (lane == 0) Sc[i * BB + j] = s;
    }
}

// ---------------------------------------------------------------- final scalars
__global__ void k5_final(const float* __restrict__ Sc, const int* __restrict__ rowcnt,
                         const float* __restrict__ err, const int* __restrict__ modes,
                         float* __restrict__ outs) {
    __shared__ float red[4];
    __shared__ float mx_sh;
    int tid = threadIdx.x;
    int lane = tid & 63, wv = tid >> 6;

    float lmin = 1e30f;
    for (int i = tid; i < BB * BB; i += 256) lmin = fminf(lmin, Sc[i]);
    #pragma unroll
    for (int off = 1; off < 64; off <<= 1) lmin = fminf(lmin, __shfl_xor(lmin, off, 64));
    if (lane == 0) red[wv] = lmin;
    __syncthreads();
    if (tid == 0) mx_sh = -fminf(fminf(red[0], red[1]), fminf(red[2], red[3]));
    __syncthreads();
    float Mx = mx_sh;

    if (wv == 0) {
        int i = lane;
        float rs = 0.f;
        for (int j = 0; j < BB; ++j) rs += __expf(Sc[i * BB + j] + Mx);
        float dg = __expf(Sc[i * BB + i] + Mx);
        float term = logf(dg / (rs + 1e-5f));
        #pragma unroll
        for (int off = 1; off < 64; off <<= 1) term += __shfl_xor(term, off, 64);
        if (lane == 0) outs[4] = 0.5f * (-(term / (float)BB));
    } else if (wv == 1 || wv == 2) {
        int mod = wv - 1;
        float s = 0.f;
        for (int m = lane; m < MM; m += 64) {
            int c = 0;
            for (int bb = 0; bb < BB; ++bb)
                c += rowcnt[(size_t)(mod * BB + bb) * MM + m];
            float p = (float)c * (1.f / (float)NTOK);
            s += p * logf(p + 1e-10f);
        }
        #pragma unroll
        for (int off = 1; off < 64; off <<= 1) s += __shfl_xor(s, off, 64);
        if (lane == 0) outs[2 + mod] = __expf(-s);
    } else {
        // error sums from 64 slots each
        float e0 = err[0 * 64 + lane], e1 = err[1 * 64 + lane];
        float e2 = err[2 * 64 + lane], e3 = err[3 * 64 + lane];
        int eq = (modes[lane] == modes[BB + lane]) ? 1 : 0;
        #pragma unroll
        for (int off = 1; off < 64; off <<= 1) {
            e0 += __shfl_xor(e0, off, 64);
            e1 += __shfl_xor(e1, off, 64);
            e2 += __shfl_xor(e2, off, 64);
            e3 += __shfl_xor(e3, off, 64);
            eq += __shfl_xor(eq, off, 64);
        }
        if (lane == 0) {
            outs[5] = (float)eq;
            const float inv = 1.f / (float)((size_t)NTOK * DD);
            float a_e = e0 * inv, av_e = e1 * inv;
            float v_e = e2 * inv, va_e = e3 * inv;
            outs[0] = 0.5f * a_e + 0.25f * av_e;
            outs[1] = 0.5f * v_e + 0.25f * va_e;
        }
    }
}

// ----------------------------------------------------------------
extern "C" void kernel_launch(void* const* d_in, const int* in_sizes, int n_in,
                              void* d_out, int out_size, void* d_ws, size_t ws_size,
                              hipStream_t stream) {
    (void)in_sizes; (void)n_in; (void)out_size; (void)ws_size;
    const float* a   = (const float*)d_in[0];
    const float* v   = (const float*)d_in[1];
    const float* emb = (const float*)d_in[2];
    float* out = (float*)d_out;
    char* ws = (char*)d_ws;

    float* pH_g   = (float*)(ws + WS_PH);
    int*   rowcnt = (int*)(ws + WS_ROWCNT);
    float* err    = (float*)(ws + WS_ERR);
    int*   idxws  = (int*)(ws + WS_IDX);
    float* esq    = (float*)(ws + WS_ESQ);
    float* Lg     = (float*)(ws + WS_LG);
    float* Sc     = (float*)(ws + WS_SC);
    int*   modes  = (int*)(ws + WS_MODE);
    unsigned short* eh = (unsigned short*)(ws + WS_EH);
    unsigned short* el = (unsigned short*)(ws + WS_EL);

    hipMemsetAsync(d_ws, 0, WS_ZERO_BYTES, stream);
    k_esq<<<MM, 64, 0, stream>>>(emb, esq, eh, el);
    k1_mfma<<<1024, 256, 0, stream>>>(a, v, eh, el, esq, pH_g, rowcnt, idxws);
    k_err<<<dim3(8192, 2), 256, 0, stream>>>(a, v, emb, idxws, out, err);
    k2_norm<<<200, 256, 0, stream>>>(pH_g, Lg);
    k3_mode<<<128, 64, 0, stream>>>(rowcnt, modes);
    k4_scode<<<BB, 256, 0, stream>>>(pH_g, Lg, Sc);
    k5_final<<<1, 256, 0, stream>>>(Sc, rowcnt, err, modes, out + (size_t)2 * NTOK * DD);
}

// Round 14
// 400.217 us; speedup vs baseline: 1.5338x; 1.5338x over previous
//
#include <hip/hip_runtime.h>
#include <math.h>

#define NTOK 32768      // B*T
#define DD 256
#define MM 400
#define BB 64
#define TT 512

// workspace layout (bytes)
#define WS_PH     0          // float [2][64][400]
#define WS_ROWCNT 204800     // int   [2][64][400]
#define WS_ERR    409600     // float [4][64]  slotted error sums
#define WS_ZERO_BYTES 410624
#define WS_IDX    410624     // int   [2][32768]
#define WS_ESQ    672768     // float [400]
#define WS_LG     674368     // float [2][64][400]
#define WS_SC     879168     // float [64][64]
#define WS_MODE   895552     // int   [128]
#define WS_EH     896064     // ushort [400][256] bf16 hi  (204800 B)
#define WS_EL     1100864    // ushort [400][256] bf16 lo  (204800 B)

typedef __attribute__((ext_vector_type(8))) short bf16x8;   // 8 bf16 = 4 VGPR
typedef __attribute__((ext_vector_type(4))) float f32x4;

// ---------------------------------------------------------------- e_sq + bf16 split of emb
__global__ void k_esq(const float* __restrict__ emb, float* __restrict__ esq,
                      unsigned short* __restrict__ eh, unsigned short* __restrict__ el) {
    int m = blockIdx.x, lane = threadIdx.x;
    float s = 0.f;
    for (int k = lane; k < DD; k += 64) {
        float e = emb[m * DD + k];
        s += e * e;
        unsigned u = __float_as_uint(e);
        unsigned short hu = (unsigned short)((u + 0x7FFFu + ((u >> 16) & 1u)) >> 16);
        float hf = __uint_as_float((unsigned)hu << 16);
        float lf = e - hf;
        unsigned ul = __float_as_uint(lf);
        unsigned short lu = (unsigned short)((ul + 0x7FFFu + ((ul >> 16) & 1u)) >> 16);
        eh[m * DD + k] = hu;
        el[m * DD + k] = lu;
    }
    #pragma unroll
    for (int off = 1; off < 64; off <<= 1) s += __shfl_xor(s, off, 64);
    if (lane == 0) esq[m] = s;
}

// ---------------------------------------------------------------- main fused kernel (MFMA + LDS-staged E)
// Ledger:
// R1  (VERIFIED): global_load_lds staging mechanism. fp32 k1=368us.
// R5/R7/R8/R10: fp32-VALU path stuck ~370us (latency-bound, occupancy-capped;
//     VGPR tiers are 64/128/256).
// R11 (VERIFIED CORRECT, perf fail 412us): bf16 split MFMA (Xh*Eh+Xh*El+Xl*Eh,
//     C/D col=lane&15 code, row=4*(lane>>4)+q token). MfmaUtil 8%, VALU 12% ->
//     pure exposed latency: per-tile 16 scattered L2 loads + 24 MFMAs chained
//     on ONE acc, no cross-tile pipelining possible at VGPR 92.
// R12 (unverified - infra failed): SAME math; E tiles staged to LDS via
//     global_load_lds (dbuf, 1 barrier/tile, T3 2-phase); G4 XOR swizzle
//     (byte^=(row&7)<<4) applied rule-21 both-sides (inverse-swizzled global
//     SOURCE, linear dest, swizzled ds_read_b128); MFMA chain split into 3
//     independent accs. E traffic /4 (block-shared), loads async bulk.
//     GATES: VGPR<=128, SQ_LDS_BANK_CONFLICT ~0.
__launch_bounds__(256)
__global__ void k1_mfma(const float* __restrict__ a, const float* __restrict__ v,
                        const unsigned short* __restrict__ eh,
                        const unsigned short* __restrict__ el,
                        const float* __restrict__ esq_g,
                        float* __restrict__ pH_g,
                        int* __restrict__ rowcnt, int* __restrict__ idxws) {
    __shared__ __align__(16) unsigned short et[2][2][16 * 256];  // 32 KB: [buf][h/l][16 codes x 256 k]
    __shared__ float pH_w[4 * MM];     // 6.4 KB
    __shared__ float xs_sh[4][16];

    const int tid = threadIdx.x;
    const int l   = tid & 63;
    const int wv  = tid >> 6;
    const int bx  = blockIdx.x;
    const int mod = bx >> 9;           // 1024 blocks: 512 per modality
    const int seg = bx & 511;
    const int blk0 = seg * 64;         // 64 tokens per block
    const int b    = seg >> 3;         // 512-token rows
    const int tok0 = blk0 + wv * 16;   // 16 tokens per wave
    const float* xg = (mod == 0) ? a : v;

    const int r = l & 15;              // A-row (token src) / B-row (code) index
    const int h = l >> 4;              // k-group
    const int myTok = tok0 + r;
    const int rowoff = r << 8;         // code-row offset in LDS tile (shorts)
    const int sw3 = (r & 7) << 3;      // G4 swizzle, short units (16B granules)

    // ---- prologue: load this lane's X k-slices, split to bf16 h/l, partial xs
    bf16x8 Xh[8], Xl[8];
    float xs_part = 0.f;
    #pragma unroll
    for (int s = 0; s < 8; ++s) {
        const float* p = xg + (size_t)myTok * DD + 32 * s + 8 * h;
        float4 f0 = *(const float4*)(p);
        float4 f1 = *(const float4*)(p + 4);
        bf16x8 th, tl;
        float e;
#define CVT(J, EV) { e = (EV); xs_part += e * e; \
        unsigned uu = __float_as_uint(e); \
        unsigned short hu = (unsigned short)((uu + 0x7FFFu + ((uu >> 16) & 1u)) >> 16); \
        float hf = __uint_as_float((unsigned)hu << 16); \
        float lf = e - hf; \
        unsigned ul = __float_as_uint(lf); \
        unsigned short lu = (unsigned short)((ul + 0x7FFFu + ((ul >> 16) & 1u)) >> 16); \
        th[J] = (short)hu; tl[J] = (short)lu; }
        CVT(0, f0.x) CVT(1, f0.y) CVT(2, f0.z) CVT(3, f0.w)
        CVT(4, f1.x) CVT(5, f1.y) CVT(6, f1.z) CVT(7, f1.w)
#undef CVT
        Xh[s] = th; Xl[s] = tl;
    }
    xs_part += __shfl_xor(xs_part, 16, 64);
    xs_part += __shfl_xor(xs_part, 32, 64);
    if (h == 0) xs_sh[wv][r] = xs_part;

    // stage tile ct into buf: 16 segs of (64 lanes x 16B). Dest linear
    // (wave-uniform base + lane*16B); source pre-swizzled so that the
    // swizzled READ (byte ^= (row&7)<<4) recovers linear columns.
#define STAGE(CT, BUF) { \
        for (int sg = wv; sg < 16; sg += 4) { \
            int hl = sg >> 3, s8 = sg & 7; \
            int u = (s8 << 6) + l; \
            int row_ = u >> 5, off16 = u & 31; \
            int colsh = (off16 << 3) ^ ((row_ & 7) << 3); \
            const unsigned short* gsrc = (hl ? el : eh) \
                + (size_t)((CT) * 16 + row_) * DD + colsh; \
            __builtin_amdgcn_global_load_lds( \
                (const __attribute__((address_space(1))) void*)gsrc, \
                (__attribute__((address_space(3))) void*)&et[BUF][hl][s8 << 9], \
                16, 0, 0); \
        } }

    // 8-slab MFMA tile body from LDS, 3 independent acc chains
#define TILE_DOT(BUF, A0, A1, A2) { \
        const unsigned short* bh_ = &et[BUF][0][rowoff]; \
        const unsigned short* bl_ = &et[BUF][1][rowoff]; \
        _Pragma("unroll") \
        for (int s = 0; s < 8; ++s) { \
            int colsh = ((h << 3) + (s << 5)) ^ sw3; \
            bf16x8 Eh_ = *(const bf16x8*)&bh_[colsh]; \
            bf16x8 El_ = *(const bf16x8*)&bl_[colsh]; \
            A0 = __builtin_amdgcn_mfma_f32_16x16x32_bf16(Xh[s], Eh_, A0, 0, 0, 0); \
            A1 = __builtin_amdgcn_mfma_f32_16x16x32_bf16(Xh[s], El_, A1, 0, 0, 0); \
            A2 = __builtin_amdgcn_mfma_f32_16x16x32_bf16(Xl[s], Eh_, A2, 0, 0, 0); \
        } }

    STAGE(0, 0)
    // first barrier also publishes xs_sh
    float xs4[4], sqx4[4];

    // ---- pass A: argmin + sum-exp (online, offset = sqrt(xs))
    float mind[4] = {1e30f, 1e30f, 1e30f, 1e30f};
    int   marg[4] = {0, 0, 0, 0};
    float se[4]   = {0.f, 0.f, 0.f, 0.f};
    for (int ct = 0; ct < 25; ++ct) {
        __syncthreads();
        if (ct == 0) {
            #pragma unroll
            for (int q = 0; q < 4; ++q) {
                xs4[q]  = xs_sh[wv][4 * h + q];
                sqx4[q] = sqrtf(xs4[q]);
            }
        }
        if (ct < 24) STAGE(ct + 1, (ct + 1) & 1)
        f32x4 a0 = {0.f,0.f,0.f,0.f}, a1 = {0.f,0.f,0.f,0.f}, a2 = {0.f,0.f,0.f,0.f};
        TILE_DOT(ct & 1, a0, a1, a2)
        const int c = ct * 16 + r;
        const float ec = esq_g[c];
        #pragma unroll
        for (int q = 0; q < 4; ++q) {
            float dot = a0[q] + a1[q] + a2[q];
            float dist = fmaf(-2.f, dot, xs4[q] + ec);
            float z = sqx4[q] - sqrtf(fmaxf(dist, 0.f));
            se[q] += __expf(z);
            if (dist < mind[q]) { mind[q] = dist; marg[q] = c; }
        }
    }
    // reduce across the 16 code-lanes of this h-group
    #pragma unroll
    for (int q = 0; q < 4; ++q) {
        float bd = mind[q]; int bi = marg[q]; float s_ = se[q];
        #pragma unroll
        for (int off = 1; off < 16; off <<= 1) {
            float od = __shfl_xor(bd, off, 64);
            int   oi = __shfl_xor(bi, off, 64);
            s_ += __shfl_xor(s_, off, 64);
            if (od < bd || (od == bd && oi < bi)) { bd = od; bi = oi; }
        }
        se[q] = 1.f / s_;           // inverse for pass B
        if (r == 0) {
            int n = tok0 + 4 * h + q;
            idxws[mod * NTOK + n] = bi;
            atomicAdd(&rowcnt[(mod * BB + b) * MM + bi], 1);
        }
    }

    // ---- pass B: recompute dots (tiles re-staged), accumulate pH
    __syncthreads();           // all waves past their last pass-A reads of buf0
    STAGE(0, 0)
    for (int ct = 0; ct < 25; ++ct) {
        __syncthreads();
        if (ct < 24) STAGE(ct + 1, (ct + 1) & 1)
        f32x4 a0 = {0.f,0.f,0.f,0.f}, a1 = {0.f,0.f,0.f,0.f}, a2 = {0.f,0.f,0.f,0.f};
        TILE_DOT(ct & 1, a0, a1, a2)
        const int c = ct * 16 + r;
        const float ec = esq_g[c];
        float val = 0.f;
        #pragma unroll
        for (int q = 0; q < 4; ++q) {
            float dot = a0[q] + a1[q] + a2[q];
            float dist = fmaf(-2.f, dot, xs4[q] + ec);
            float z = sqx4[q] - sqrtf(fmaxf(dist, 0.f));
            val = fmaf(__expf(z), se[q], val);
        }
        val += __shfl_xor(val, 16, 64);
        val += __shfl_xor(val, 32, 64);
        if (h == 0) pH_w[wv * MM + c] = val;
    }
#undef TILE_DOT
#undef STAGE

    __syncthreads();
    for (int m = tid; m < MM; m += 256) {
        float s = pH_w[m] + pH_w[MM + m] + pH_w[2 * MM + m] + pH_w[3 * MM + m];
        atomicAdd(&pH_g[(size_t)(mod * BB + b) * MM + m], s);
    }
}

// ---------------------------------------------------------------- quantized outputs + error sums
__global__ void k_err(const float* __restrict__ a, const float* __restrict__ v,
                      const float* __restrict__ emb, const int* __restrict__ idxws,
                      float* __restrict__ out, float* __restrict__ err) {
    const int mod = blockIdx.y;
    const int tid = threadIdx.x;
    const int gid = blockIdx.x * 256 + tid;
    const int n  = gid >> 6;
    const int d4 = (gid & 63) << 2;
    const int ia = idxws[n];
    const int iv = idxws[NTOK + n];
    const int own = (mod == 0) ? ia : iv;
    const int oth = (mod == 0) ? iv : ia;
    const float* x = (mod == 0) ? a : v;

    float4 xv = *(const float4*)(x + (size_t)n * DD + d4);
    float4 qo = *(const float4*)(emb + (size_t)own * DD + d4);
    float4 qc = *(const float4*)(emb + (size_t)oth * DD + d4);
    *(float4*)(out + (size_t)mod * NTOK * DD + (size_t)n * DD + d4) = qo;

    float eo, ec;
    { float dx = xv.x - qo.x, dy = xv.y - qo.y, dz = xv.z - qo.z, dw = xv.w - qo.w;
      eo = dx * dx + dy * dy + dz * dz + dw * dw; }
    { float dx = xv.x - qc.x, dy = xv.y - qc.y, dz = xv.z - qc.z, dw = xv.w - qc.w;
      ec = dx * dx + dy * dy + dz * dz + dw * dw; }

    #pragma unroll
    for (int off = 1; off < 64; off <<= 1) {
        eo += __shfl_xor(eo, off, 64);
        ec += __shfl_xor(ec, off, 64);
    }
    __shared__ float ro[4], rc[4];
    if ((tid & 63) == 0) { ro[tid >> 6] = eo; rc[tid >> 6] = ec; }
    __syncthreads();
    if (tid == 0) {
        int slot = blockIdx.x & 63;    // 64-way slotted: contention /64
        atomicAdd(&err[(mod * 2 + 0) * 64 + slot], ro[0] + ro[1] + ro[2] + ro[3]);
        atomicAdd(&err[(mod * 2 + 1) * 64 + slot], rc[0] + rc[1] + rc[2] + rc[3]);
    }
}

// ---------------------------------------------------------------- normalize pH, logs
__global__ void k2_norm(float* __restrict__ pH, float* __restrict__ Lg) {
    int i = blockIdx.x * 256 + threadIdx.x;
    if (i < 2 * BB * MM) {
        float p = pH[i] * (1.f / TT);
        pH[i] = p;
        Lg[i] = logf(p + 1e-10f);
    }
}

// ---------------------------------------------------------------- per-row mode
__global__ void k3_mode(const int* __restrict__ rowcnt, int* __restrict__ modes) {
    int r = blockIdx.x, lane = threadIdx.x;
    const int* cnt = rowcnt + r * MM;
    int bc = -1, bi = 0x7fffffff;
    for (int m = lane; m < MM; m += 64) {
        int c = cnt[m];
        if (c > bc) { bc = c; bi = m; }
    }
    #pragma unroll
    for (int off = 1; off < 64; off <<= 1) {
        int oc = __shfl_xor(bc, off, 64);
        int oi = __shfl_xor(bi, off, 64);
        if (oc > bc || (oc == bc && oi < bi)) { bc = oc; bi = oi; }
    }
    if (lane == 0) modes[r] = bi;
}

// ---------------------------------------------------------------- Scode (64x64, K=400, x2 terms)
__global__ void k4_scode(const float* __restrict__ pH, const float* __restrict__ Lg,
                         float* __restrict__ Sc) {
    int i = blockIdx.x;
    int tid = threadIdx.x, lane = tid & 63, wv = tid >> 6;
    const float* aPH = pH + (size_t)i * MM;
    const float* vPH = pH + (size_t)(BB + i) * MM;
    for (int jj = 0; jj < 16; ++jj) {
        int j = wv * 16 + jj;
        const float* Lv = Lg + (size_t)(BB + j) * MM;
        const float* La = Lg + (size_t)j * MM;
        float s = 0.f;
        for (int m = lane; m < MM; m += 64)
            s += aPH[m] * Lv[m] + vPH[m] * La[m];
        #pragma unroll
        for (int off = 1; off < 64; off <<= 1) s += __shfl_xor(s, off, 64);
        if (lane == 0) Sc[i * BB + j] = s;
    }
}

// ---------------------------------------------------------------- final scalars
__global__ void k5_final(const float* __restrict__ Sc, const int* __restrict__ rowcnt,
                         const float* __restrict__ err, const int* __restrict__ modes,
                         float* __restrict__ outs) {
    __shared__ float red[4];
    __shared__ float mx_sh;
    int tid = threadIdx.x;
    int lane = tid & 63, wv = tid >> 6;

    float lmin = 1e30f;
    for (int i = tid; i < BB * BB; i += 256) lmin = fminf(lmin, Sc[i]);
    #pragma unroll
    for (int off = 1; off < 64; off <<= 1) lmin = fminf(lmin, __shfl_xor(lmin, off, 64));
    if (lane == 0) red[wv] = lmin;
    __syncthreads();
    if (tid == 0) mx_sh = -fminf(fminf(red[0], red[1]), fminf(red[2], red[3]));
    __syncthreads();
    float Mx = mx_sh;

    if (wv == 0) {
        int i = lane;
        float rs = 0.f;
        for (int j = 0; j < BB; ++j) rs += __expf(Sc[i * BB + j] + Mx);
        float dg = __expf(Sc[i * BB + i] + Mx);
        float term = logf(dg / (rs + 1e-5f));
        #pragma unroll
        for (int off = 1; off < 64; off <<= 1) term += __shfl_xor(term, off, 64);
        if (lane == 0) outs[4] = 0.5f * (-(term / (float)BB));
    } else if (wv == 1 || wv == 2) {
        int mod = wv - 1;
        float s = 0.f;
        for (int m = lane; m < MM; m += 64) {
            int c = 0;
            for (int bb = 0; bb < BB; ++bb)
                c += rowcnt[(size_t)(mod * BB + bb) * MM + m];
            float p = (float)c * (1.f / (float)NTOK);
            s += p * logf(p + 1e-10f);
        }
        #pragma unroll
        for (int off = 1; off < 64; off <<= 1) s += __shfl_xor(s, off, 64);
        if (lane == 0) outs[2 + mod] = __expf(-s);
    } else {
        // error sums from 64 slots each
        float e0 = err[0 * 64 + lane], e1 = err[1 * 64 + lane];
        float e2 = err[2 * 64 + lane], e3 = err[3 * 64 + lane];
        int eq = (modes[lane] == modes[BB + lane]) ? 1 : 0;
        #pragma unroll
        for (int off = 1; off < 64; off <<= 1) {
            e0 += __shfl_xor(e0, off, 64);
            e1 += __shfl_xor(e1, off, 64);
            e2 += __shfl_xor(e2, off, 64);
            e3 += __shfl_xor(e3, off, 64);
            eq += __shfl_xor(eq, off, 64);
        }
        if (lane == 0) {
            outs[5] = (float)eq;
            const float inv = 1.f / (float)((size_t)NTOK * DD);
            float a_e = e0 * inv, av_e = e1 * inv;
            float v_e = e2 * inv, va_e = e3 * inv;
            outs[0] = 0.5f * a_e + 0.25f * av_e;
            outs[1] = 0.5f * v_e + 0.25f * va_e;
        }
    }
}

// ----------------------------------------------------------------
extern "C" void kernel_launch(void* const* d_in, const int* in_sizes, int n_in,
                              void* d_out, int out_size, void* d_ws, size_t ws_size,
                              hipStream_t stream) {
    (void)in_sizes; (void)n_in; (void)out_size; (void)ws_size;
    const float* a   = (const float*)d_in[0];
    const float* v   = (const float*)d_in[1];
    const float* emb = (const float*)d_in[2];
    float* out = (float*)d_out;
    char* ws = (char*)d_ws;

    float* pH_g   = (float*)(ws + WS_PH);
    int*   rowcnt = (int*)(ws + WS_ROWCNT);
    float* err    = (float*)(ws + WS_ERR);
    int*   idxws  = (int*)(ws + WS_IDX);
    float* esq    = (float*)(ws + WS_ESQ);
    float* Lg     = (float*)(ws + WS_LG);
    float* Sc     = (float*)(ws + WS_SC);
    int*   modes  = (int*)(ws + WS_MODE);
    unsigned short* eh = (unsigned short*)(ws + WS_EH);
    unsigned short* el = (unsigned short*)(ws + WS_EL);

    hipMemsetAsync(d_ws, 0, WS_ZERO_BYTES, stream);
    k_esq<<<MM, 64, 0, stream>>>(emb, esq, eh, el);
    k1_mfma<<<1024, 256, 0, stream>>>(a, v, eh, el, esq, pH_g, rowcnt, idxws);
    k_err<<<dim3(8192, 2), 256, 0, stream>>>(a, v, emb, idxws, out, err);
    k2_norm<<<200, 256, 0, stream>>>(pH_g, Lg);
    k3_mode<<<128, 64, 0, stream>>>(rowcnt, modes);
    k4_scode<<<BB, 256, 0, stream>>>(pH_g, Lg, Sc);
    k5_final<<<1, 256, 0, stream>>>(Sc, rowcnt, err, modes, out + (size_t)2 * NTOK * DD);
}

// Round 16
// 340.510 us; speedup vs baseline: 1.8027x; 1.1753x over previous
//
#include <hip/hip_runtime.h>
#include <math.h>

#define NTOK 32768      // B*T
#define DD 256
#define MM 400
#define BB 64
#define TT 512

// workspace layout (bytes)
#define WS_PH     0          // float [2][64][400]
#define WS_ROWCNT 204800     // int   [2][64][400]
#define WS_ERR    409600     // float [4][64]  slotted error sums
#define WS_ZERO_BYTES 410624
#define WS_IDX    410624     // int   [2][32768]
#define WS_ESQ    672768     // float [400]
#define WS_LG     674368     // float [2][64][400]
#define WS_SC     879168     // float [64][64]
#define WS_MODE   895552     // int   [128]
#define WS_EH     896064     // ushort [400][256] bf16 hi  (204800 B)
#define WS_EL     1100864    // ushort [400][256] bf16 lo  (204800 B)

typedef __attribute__((ext_vector_type(8))) short bf16x8;   // 8 bf16 = 4 VGPR
typedef __attribute__((ext_vector_type(4))) float f32x4;

// ---------------------------------------------------------------- e_sq + bf16 split of emb
__global__ void k_esq(const float* __restrict__ emb, float* __restrict__ esq,
                      unsigned short* __restrict__ eh, unsigned short* __restrict__ el) {
    int m = blockIdx.x, lane = threadIdx.x;
    float s = 0.f;
    for (int k = lane; k < DD; k += 64) {
        float e = emb[m * DD + k];
        s += e * e;
        unsigned u = __float_as_uint(e);
        unsigned short hu = (unsigned short)((u + 0x7FFFu + ((u >> 16) & 1u)) >> 16);
        float hf = __uint_as_float((unsigned)hu << 16);
        float lf = e - hf;
        unsigned ul = __float_as_uint(lf);
        unsigned short lu = (unsigned short)((ul + 0x7FFFu + ((ul >> 16) & 1u)) >> 16);
        eh[m * DD + k] = hu;
        el[m * DD + k] = lu;
    }
    #pragma unroll
    for (int off = 1; off < 64; off <<= 1) s += __shfl_xor(s, off, 64);
    if (lane == 0) esq[m] = s;
}

// ---------------------------------------------------------------- main fused kernel (MFMA + LDS-staged E)
// Ledger:
// R1  (VERIFIED): global_load_lds staging mechanism. fp32 k1=368us.
// R5/R7/R8/R10: fp32-VALU path stuck ~370us (latency-bound, occupancy-capped;
//     VGPR tiers are 64/128/256).
// R11 (VERIFIED CORRECT, 412us): bf16 split MFMA; scattered L2 loads exposed.
// R12 (VERIFIED WIN 412->180us, total 400): E tiles staged to LDS via
//     global_load_lds (dbuf, 1 barrier/tile); G4 XOR swizzle rule-21
//     both-sides; 3 independent acc chains. MfmaUtil 8->18.7%, VALU 54%,
//     VGPR 96. Residual bank aliasing 1.3e7 cyc (~11%) - b128 inherent,
//     secondary. k1 is ~5x MFMA floor (34us); next k1 levers are VALU trim
//     and the two-pass recompute - both medium-risk, deferred.
// R14/R15 (this): k1 UNTOUCHED (control: expect identical counter row).
//     Tail attack - k_err v2 below. R15 fixes the nontemporal-store type
//     (builtin needs a clang ext-vector, not HIP float4).
__launch_bounds__(256)
__global__ void k1_mfma(const float* __restrict__ a, const float* __restrict__ v,
                        const unsigned short* __restrict__ eh,
                        const unsigned short* __restrict__ el,
                        const float* __restrict__ esq_g,
                        float* __restrict__ pH_g,
                        int* __restrict__ rowcnt, int* __restrict__ idxws) {
    __shared__ __align__(16) unsigned short et[2][2][16 * 256];  // 32 KB: [buf][h/l][16 codes x 256 k]
    __shared__ float pH_w[4 * MM];     // 6.4 KB
    __shared__ float xs_sh[4][16];

    const int tid = threadIdx.x;
    const int l   = tid & 63;
    const int wv  = tid >> 6;
    const int bx  = blockIdx.x;
    const int mod = bx >> 9;           // 1024 blocks: 512 per modality
    const int seg = bx & 511;
    const int blk0 = seg * 64;         // 64 tokens per block
    const int b    = seg >> 3;         // 512-token rows
    const int tok0 = blk0 + wv * 16;   // 16 tokens per wave
    const float* xg = (mod == 0) ? a : v;

    const int r = l & 15;              // A-row (token src) / B-row (code) index
    const int h = l >> 4;              // k-group
    const int myTok = tok0 + r;
    const int rowoff = r << 8;         // code-row offset in LDS tile (shorts)
    const int sw3 = (r & 7) << 3;      // G4 swizzle, short units (16B granules)

    // ---- prologue: load this lane's X k-slices, split to bf16 h/l, partial xs
    bf16x8 Xh[8], Xl[8];
    float xs_part = 0.f;
    #pragma unroll
    for (int s = 0; s < 8; ++s) {
        const float* p = xg + (size_t)myTok * DD + 32 * s + 8 * h;
        float4 f0 = *(const float4*)(p);
        float4 f1 = *(const float4*)(p + 4);
        bf16x8 th, tl;
        float e;
#define CVT(J, EV) { e = (EV); xs_part += e * e; \
        unsigned uu = __float_as_uint(e); \
        unsigned short hu = (unsigned short)((uu + 0x7FFFu + ((uu >> 16) & 1u)) >> 16); \
        float hf = __uint_as_float((unsigned)hu << 16); \
        float lf = e - hf; \
        unsigned ul = __float_as_uint(lf); \
        unsigned short lu = (unsigned short)((ul + 0x7FFFu + ((ul >> 16) & 1u)) >> 16); \
        th[J] = (short)hu; tl[J] = (short)lu; }
        CVT(0, f0.x) CVT(1, f0.y) CVT(2, f0.z) CVT(3, f0.w)
        CVT(4, f1.x) CVT(5, f1.y) CVT(6, f1.z) CVT(7, f1.w)
#undef CVT
        Xh[s] = th; Xl[s] = tl;
    }
    xs_part += __shfl_xor(xs_part, 16, 64);
    xs_part += __shfl_xor(xs_part, 32, 64);
    if (h == 0) xs_sh[wv][r] = xs_part;

    // stage tile ct into buf: 16 segs of (64 lanes x 16B). Dest linear
    // (wave-uniform base + lane*16B); source pre-swizzled so that the
    // swizzled READ (byte ^= (row&7)<<4) recovers linear columns.
#define STAGE(CT, BUF) { \
        for (int sg = wv; sg < 16; sg += 4) { \
            int hl = sg >> 3, s8 = sg & 7; \
            int u = (s8 << 6) + l; \
            int row_ = u >> 5, off16 = u & 31; \
            int colsh = (off16 << 3) ^ ((row_ & 7) << 3); \
            const unsigned short* gsrc = (hl ? el : eh) \
                + (size_t)((CT) * 16 + row_) * DD + colsh; \
            __builtin_amdgcn_global_load_lds( \
                (const __attribute__((address_space(1))) void*)gsrc, \
                (__attribute__((address_space(3))) void*)&et[BUF][hl][s8 << 9], \
                16, 0, 0); \
        } }

    // 8-slab MFMA tile body from LDS, 3 independent acc chains
#define TILE_DOT(BUF, A0, A1, A2) { \
        const unsigned short* bh_ = &et[BUF][0][rowoff]; \
        const unsigned short* bl_ = &et[BUF][1][rowoff]; \
        _Pragma("unroll") \
        for (int s = 0; s < 8; ++s) { \
            int colsh = ((h << 3) + (s << 5)) ^ sw3; \
            bf16x8 Eh_ = *(const bf16x8*)&bh_[colsh]; \
            bf16x8 El_ = *(const bf16x8*)&bl_[colsh]; \
            A0 = __builtin_amdgcn_mfma_f32_16x16x32_bf16(Xh[s], Eh_, A0, 0, 0, 0); \
            A1 = __builtin_amdgcn_mfma_f32_16x16x32_bf16(Xh[s], El_, A1, 0, 0, 0); \
            A2 = __builtin_amdgcn_mfma_f32_16x16x32_bf16(Xl[s], Eh_, A2, 0, 0, 0); \
        } }

    STAGE(0, 0)
    // first barrier also publishes xs_sh
    float xs4[4], sqx4[4];

    // ---- pass A: argmin + sum-exp (online, offset = sqrt(xs))
    float mind[4] = {1e30f, 1e30f, 1e30f, 1e30f};
    int   marg[4] = {0, 0, 0, 0};
    float se[4]   = {0.f, 0.f, 0.f, 0.f};
    for (int ct = 0; ct < 25; ++ct) {
        __syncthreads();
        if (ct == 0) {
            #pragma unroll
            for (int q = 0; q < 4; ++q) {
                xs4[q]  = xs_sh[wv][4 * h + q];
                sqx4[q] = sqrtf(xs4[q]);
            }
        }
        if (ct < 24) STAGE(ct + 1, (ct + 1) & 1)
        f32x4 a0 = {0.f,0.f,0.f,0.f}, a1 = {0.f,0.f,0.f,0.f}, a2 = {0.f,0.f,0.f,0.f};
        TILE_DOT(ct & 1, a0, a1, a2)
        const int c = ct * 16 + r;
        const float ec = esq_g[c];
        #pragma unroll
        for (int q = 0; q < 4; ++q) {
            float dot = a0[q] + a1[q] + a2[q];
            float dist = fmaf(-2.f, dot, xs4[q] + ec);
            float z = sqx4[q] - sqrtf(fmaxf(dist, 0.f));
            se[q] += __expf(z);
            if (dist < mind[q]) { mind[q] = dist; marg[q] = c; }
        }
    }
    // reduce across the 16 code-lanes of this h-group
    #pragma unroll
    for (int q = 0; q < 4; ++q) {
        float bd = mind[q]; int bi = marg[q]; float s_ = se[q];
        #pragma unroll
        for (int off = 1; off < 16; off <<= 1) {
            float od = __shfl_xor(bd, off, 64);
            int   oi = __shfl_xor(bi, off, 64);
            s_ += __shfl_xor(s_, off, 64);
            if (od < bd || (od == bd && oi < bi)) { bd = od; bi = oi; }
        }
        se[q] = 1.f / s_;           // inverse for pass B
        if (r == 0) {
            int n = tok0 + 4 * h + q;
            idxws[mod * NTOK + n] = bi;
            atomicAdd(&rowcnt[(mod * BB + b) * MM + bi], 1);
        }
    }

    // ---- pass B: recompute dots (tiles re-staged), accumulate pH
    __syncthreads();           // all waves past their last pass-A reads of buf0
    STAGE(0, 0)
    for (int ct = 0; ct < 25; ++ct) {
        __syncthreads();
        if (ct < 24) STAGE(ct + 1, (ct + 1) & 1)
        f32x4 a0 = {0.f,0.f,0.f,0.f}, a1 = {0.f,0.f,0.f,0.f}, a2 = {0.f,0.f,0.f,0.f};
        TILE_DOT(ct & 1, a0, a1, a2)
        const int c = ct * 16 + r;
        const float ec = esq_g[c];
        float val = 0.f;
        #pragma unroll
        for (int q = 0; q < 4; ++q) {
            float dot = a0[q] + a1[q] + a2[q];
            float dist = fmaf(-2.f, dot, xs4[q] + ec);
            float z = sqx4[q] - sqrtf(fmaxf(dist, 0.f));
            val = fmaf(__expf(z), se[q], val);
        }
        val += __shfl_xor(val, 16, 64);
        val += __shfl_xor(val, 32, 64);
        if (h == 0) pH_w[wv * MM + c] = val;
    }
#undef TILE_DOT
#undef STAGE

    __syncthreads();
    for (int m = tid; m < MM; m += 256) {
        float s = pH_w[m] + pH_w[MM + m] + pH_w[2 * MM + m] + pH_w[3 * MM + m];
        atomicAdd(&pH_g[(size_t)(mod * BB + b) * MM + m], s);
    }
}

// ---------------------------------------------------------------- quantized outputs + error sums
// R14 v2 (R15: store via clang ext-vector f32x4 - the nontemporal builtin
// rejects HIP_vector_type float4): (a) out written via nontemporal store -
// 64 MB of streaming writes no longer thrash the 32 MB aggregate L2 that
// the emb gathers depend on; (b) 4 tokens per wave (unrolled, grid /4) ->
// 12 independent loads in flight per thread instead of 3, 4x fewer blocks.
// Math identical; only atomic slot grouping order changes (fp32 ~1e-7).
__global__ void k_err(const float* __restrict__ a, const float* __restrict__ v,
                      const float* __restrict__ emb, const int* __restrict__ idxws,
                      float* __restrict__ out, float* __restrict__ err) {
    const int mod = blockIdx.y;
    const int tid = threadIdx.x;
    const int wv  = tid >> 6;
    const int d4  = (tid & 63) << 2;
    const float* x = (mod == 0) ? a : v;
    float* outm = out + (size_t)mod * NTOK * DD;

    float eo = 0.f, ec = 0.f;
    #pragma unroll
    for (int it = 0; it < 4; ++it) {
        const int n = blockIdx.x * 16 + (it << 2) + wv;
        const int ia = idxws[n];
        const int iv = idxws[NTOK + n];
        const int own = (mod == 0) ? ia : iv;
        const int oth = (mod == 0) ? iv : ia;

        float4 xv = *(const float4*)(x + (size_t)n * DD + d4);
        float4 qo = *(const float4*)(emb + (size_t)own * DD + d4);
        float4 qc = *(const float4*)(emb + (size_t)oth * DD + d4);
        f32x4 qv = {qo.x, qo.y, qo.z, qo.w};
        __builtin_nontemporal_store(qv, (f32x4*)(outm + (size_t)n * DD + d4));

        { float dx = xv.x - qo.x, dy = xv.y - qo.y, dz = xv.z - qo.z, dw = xv.w - qo.w;
          eo += dx * dx + dy * dy + dz * dz + dw * dw; }
        { float dx = xv.x - qc.x, dy = xv.y - qc.y, dz = xv.z - qc.z, dw = xv.w - qc.w;
          ec += dx * dx + dy * dy + dz * dz + dw * dw; }
    }

    #pragma unroll
    for (int off = 1; off < 64; off <<= 1) {
        eo += __shfl_xor(eo, off, 64);
        ec += __shfl_xor(ec, off, 64);
    }
    __shared__ float ro[4], rc[4];
    if ((tid & 63) == 0) { ro[wv] = eo; rc[wv] = ec; }
    __syncthreads();
    if (tid == 0) {
        int slot = blockIdx.x & 63;    // 64-way slotted: contention /64
        atomicAdd(&err[(mod * 2 + 0) * 64 + slot], ro[0] + ro[1] + ro[2] + ro[3]);
        atomicAdd(&err[(mod * 2 + 1) * 64 + slot], rc[0] + rc[1] + rc[2] + rc[3]);
    }
}

// ---------------------------------------------------------------- normalize pH, logs
__global__ void k2_norm(float* __restrict__ pH, float* __restrict__ Lg) {
    int i = blockIdx.x * 256 + threadIdx.x;
    if (i < 2 * BB * MM) {
        float p = pH[i] * (1.f / TT);
        pH[i] = p;
        Lg[i] = logf(p + 1e-10f);
    }
}

// ---------------------------------------------------------------- per-row mode
__global__ void k3_mode(const int* __restrict__ rowcnt, int* __restrict__ modes) {
    int r = blockIdx.x, lane = threadIdx.x;
    const int* cnt = rowcnt + r * MM;
    int bc = -1, bi = 0x7fffffff;
    for (int m = lane; m < MM; m += 64) {
        int c = cnt[m];
        if (c > bc) { bc = c; bi = m; }
    }
    #pragma unroll
    for (int off = 1; off < 64; off <<= 1) {
        int oc = __shfl_xor(bc, off, 64);
        int oi = __shfl_xor(bi, off, 64);
        if (oc > bc || (oc == bc && oi < bi)) { bc = oc; bi = oi; }
    }
    if (lane == 0) modes[r] = bi;
}

// ---------------------------------------------------------------- Scode (64x64, K=400, x2 terms)
__global__ void k4_scode(const float* __restrict__ pH, const float* __restrict__ Lg,
                         float* __restrict__ Sc) {
    int i = blockIdx.x;
    int tid = threadIdx.x, lane = tid & 63, wv = tid >> 6;
    const float* aPH = pH + (size_t)i * MM;
    const float* vPH = pH + (size_t)(BB + i) * MM;
    for (int jj = 0; jj < 16; ++jj) {
        int j = wv * 16 + jj;
        const float* Lv = Lg + (size_t)(BB + j) * MM;
        const float* La = Lg + (size_t)j * MM;
        float s = 0.f;
        for (int m = lane; m < MM; m += 64)
            s += aPH[m] * Lv[m] + vPH[m] * La[m];
        #pragma unroll
        for (int off = 1; off < 64; off <<= 1) s += __shfl_xor(s, off, 64);
        if (lane == 0) Sc[i * BB + j] = s;
    }
}

// ---------------------------------------------------------------- final scalars
__global__ void k5_final(const float* __restrict__ Sc, const int* __restrict__ rowcnt,
                         const float* __restrict__ err, const int* __restrict__ modes,
                         float* __restrict__ outs) {
    __shared__ float red[4];
    __shared__ float mx_sh;
    int tid = threadIdx.x;
    int lane = tid & 63, wv = tid >> 6;

    float lmin = 1e30f;
    for (int i = tid; i < BB * BB; i += 256) lmin = fminf(lmin, Sc[i]);
    #pragma unroll
    for (int off = 1; off < 64; off <<= 1) lmin = fminf(lmin, __shfl_xor(lmin, off, 64));
    if (lane == 0) red[wv] = lmin;
    __syncthreads();
    if (tid == 0) mx_sh = -fminf(fminf(red[0], red[1]), fminf(red[2], red[3]));
    __syncthreads();
    float Mx = mx_sh;

    if (wv == 0) {
        int i = lane;
        float rs = 0.f;
        for (int j = 0; j < BB; ++j) rs += __expf(Sc[i * BB + j] + Mx);
        float dg = __expf(Sc[i * BB + i] + Mx);
        float term = logf(dg / (rs + 1e-5f));
        #pragma unroll
        for (int off = 1; off < 64; off <<= 1) term += __shfl_xor(term, off, 64);
        if (lane == 0) outs[4] = 0.5f * (-(term / (float)BB));
    } else if (wv == 1 || wv == 2) {
        int mod = wv - 1;
        float s = 0.f;
        for (int m = lane; m < MM; m += 64) {
            int c = 0;
            for (int bb = 0; bb < BB; ++bb)
                c += rowcnt[(size_t)(mod * BB + bb) * MM + m];
            float p = (float)c * (1.f / (float)NTOK);
            s += p * logf(p + 1e-10f);
        }
        #pragma unroll
        for (int off = 1; off < 64; off <<= 1) s += __shfl_xor(s, off, 64);
        if (lane == 0) outs[2 + mod] = __expf(-s);
    } else {
        // error sums from 64 slots each
        float e0 = err[0 * 64 + lane], e1 = err[1 * 64 + lane];
        float e2 = err[2 * 64 + lane], e3 = err[3 * 64 + lane];
        int eq = (modes[lane] == modes[BB + lane]) ? 1 : 0;
        #pragma unroll
        for (int off = 1; off < 64; off <<= 1) {
            e0 += __shfl_xor(e0, off, 64);
            e1 += __shfl_xor(e1, off, 64);
            e2 += __shfl_xor(e2, off, 64);
            e3 += __shfl_xor(e3, off, 64);
            eq += __shfl_xor(eq, off, 64);
        }
        if (lane == 0) {
            outs[5] = (float)eq;
            const float inv = 1.f / (float)((size_t)NTOK * DD);
            float a_e = e0 * inv, av_e = e1 * inv;
            float v_e = e2 * inv, va_e = e3 * inv;
            outs[0] = 0.5f * a_e + 0.25f * av_e;
            outs[1] = 0.5f * v_e + 0.25f * va_e;
        }
    }
}

// ----------------------------------------------------------------
extern "C" void kernel_launch(void* const* d_in, const int* in_sizes, int n_in,
                              void* d_out, int out_size, void* d_ws, size_t ws_size,
                              hipStream_t stream) {
    (void)in_sizes; (void)n_in; (void)out_size; (void)ws_size;
    const float* a   = (const float*)d_in[0];
    const float* v   = (const float*)d_in[1];
    const float* emb = (const float*)d_in[2];
    float* out = (float*)d_out;
    char* ws = (char*)d_ws;

    float* pH_g   = (float*)(ws + WS_PH);
    int*   rowcnt = (int*)(ws + WS_ROWCNT);
    float* err    = (float*)(ws + WS_ERR);
    int*   idxws  = (int*)(ws + WS_IDX);
    float* esq    = (float*)(ws + WS_ESQ);
    float* Lg     = (float*)(ws + WS_LG);
    float* Sc     = (float*)(ws + WS_SC);
    int*   modes  = (int*)(ws + WS_MODE);
    unsigned short* eh = (unsigned short*)(ws + WS_EH);
    unsigned short* el = (unsigned short*)(ws + WS_EL);

    hipMemsetAsync(d_ws, 0, WS_ZERO_BYTES, stream);
    k_esq<<<MM, 64, 0, stream>>>(emb, esq, eh, el);
    k1_mfma<<<1024, 256, 0, stream>>>(a, v, eh, el, esq, pH_g, rowcnt, idxws);
    k_err<<<dim3(2048, 2), 256, 0, stream>>>(a, v, emb, idxws, out, err);
    k2_norm<<<200, 256, 0, stream>>>(pH_g, Lg);
    k3_mode<<<128, 64, 0, stream>>>(rowcnt, modes);
    k4_scode<<<BB, 256, 0, stream>>>(pH_g, Lg, Sc);
    k5_final<<<1, 256, 0, stream>>>(Sc, rowcnt, err, modes, out + (size_t)2 * NTOK * DD);
}

// Round 17
// 327.930 us; speedup vs baseline: 1.8719x; 1.0384x over previous
//
#include <hip/hip_runtime.h>
#include <hip/hip_fp16.h>
#include <math.h>

#define NTOK 32768      // B*T
#define DD 256
#define MM 400
#define BB 64
#define TT 512

// workspace layout (bytes)
#define WS_PH     0          // float [2][64][400]
#define WS_ROWCNT 204800     // int   [2][64][400]
#define WS_ERR    409600     // float [4][64]  slotted error sums
#define WS_ZERO_BYTES 410624
#define WS_IDX    410624     // int   [2][32768]
#define WS_ESQ    672768     // float [400]
#define WS_LG     674368     // float [2][64][400]
#define WS_SC     879168     // float [64][64]
#define WS_MODE   895552     // int   [128]
#define WS_EH     896064     // ushort [400][256] bf16 hi  (204800 B)
#define WS_EL     1100864    // ushort [400][256] bf16 lo  (204800 B)

typedef __attribute__((ext_vector_type(8))) short bf16x8;   // 8 bf16 = 4 VGPR
typedef __attribute__((ext_vector_type(4))) float f32x4;

// ---------------------------------------------------------------- e_sq + bf16 split of emb
__global__ void k_esq(const float* __restrict__ emb, float* __restrict__ esq,
                      unsigned short* __restrict__ eh, unsigned short* __restrict__ el) {
    int m = blockIdx.x, lane = threadIdx.x;
    float s = 0.f;
    for (int k = lane; k < DD; k += 64) {
        float e = emb[m * DD + k];
        s += e * e;
        unsigned u = __float_as_uint(e);
        unsigned short hu = (unsigned short)((u + 0x7FFFu + ((u >> 16) & 1u)) >> 16);
        float hf = __uint_as_float((unsigned)hu << 16);
        float lf = e - hf;
        unsigned ul = __float_as_uint(lf);
        unsigned short lu = (unsigned short)((ul + 0x7FFFu + ((ul >> 16) & 1u)) >> 16);
        eh[m * DD + k] = hu;
        el[m * DD + k] = lu;
    }
    #pragma unroll
    for (int off = 1; off < 64; off <<= 1) s += __shfl_xor(s, off, 64);
    if (lane == 0) esq[m] = s;
}

// ---------------------------------------------------------------- main fused kernel (MFMA + LDS-staged E)
// Ledger:
// R1  (VERIFIED): global_load_lds staging. fp32 k1=368us.
// R5/R7/R8/R10: fp32 path stuck ~370us; VGPR tiers 64/128/256.
// R11 (VERIFIED, 412us): bf16 split MFMA; scattered loads exposed.
// R12 (VERIFIED WIN 180us): LDS-staged E (dbuf 1 barrier/tile, G4 swizzle
//     rule-21 both-sides), 3 acc chains. MfmaUtil 18.7, VALU 54, VGPR 96.
// R15 (VERIFIED WIN total 340): k_err v2 (nontemporal out + 4 tok/wave).
// R16 (this): SINGLE-PASS k1 - pass B (full 25-tile recompute for pH,
//     ~90us) eliminated. Lane stores its 100 softmax exponents z (4 tok x
//     25 tiles) as fp16 pairs in 50 VGPRs (z in [-0.15,0.05], fp16 err
//     ~5e-5 on exp). To stay <=128 VGPR: drop the Xl*Eh MFMA chain
//     (dropped-term std ~2.8e-5 vs inter-code dot spread 0.046 - same
//     tie-flip regime). BOTH zst loops fully unrolled (rule #20: dynamic
//     index -> scratch). Pass A ordering byte-identical to R12.
//     GATES: VGPR<=128, absmax ~0.0049 passed.
__launch_bounds__(256)
__global__ void k1_mfma(const float* __restrict__ a, const float* __restrict__ v,
                        const unsigned short* __restrict__ eh,
                        const unsigned short* __restrict__ el,
                        const float* __restrict__ esq_g,
                        float* __restrict__ pH_g,
                        int* __restrict__ rowcnt, int* __restrict__ idxws) {
    __shared__ __align__(16) unsigned short et[2][2][16 * 256];  // 32 KB: [buf][h/l][16 codes x 256 k]
    __shared__ float pH_w[4 * MM];     // 6.4 KB
    __shared__ float xs_sh[4][16];

    const int tid = threadIdx.x;
    const int l   = tid & 63;
    const int wv  = tid >> 6;
    const int bx  = blockIdx.x;
    const int mod = bx >> 9;           // 1024 blocks: 512 per modality
    const int seg = bx & 511;
    const int blk0 = seg * 64;         // 64 tokens per block
    const int b    = seg >> 3;         // 512-token rows
    const int tok0 = blk0 + wv * 16;   // 16 tokens per wave
    const float* xg = (mod == 0) ? a : v;

    const int r = l & 15;              // A-row (token src) / B-row (code) index
    const int h = l >> 4;              // k-group
    const int myTok = tok0 + r;
    const int rowoff = r << 8;         // code-row offset in LDS tile (shorts)
    const int sw3 = (r & 7) << 3;      // G4 swizzle, short units (16B granules)

    // ---- prologue: load this lane's X k-slices, bf16 hi only, partial xs
    bf16x8 Xh[8];
    float xs_part = 0.f;
    #pragma unroll
    for (int s = 0; s < 8; ++s) {
        const float* p = xg + (size_t)myTok * DD + 32 * s + 8 * h;
        float4 f0 = *(const float4*)(p);
        float4 f1 = *(const float4*)(p + 4);
        bf16x8 th;
        float e;
#define CVT(J, EV) { e = (EV); xs_part += e * e; \
        unsigned uu = __float_as_uint(e); \
        th[J] = (short)(unsigned short)((uu + 0x7FFFu + ((uu >> 16) & 1u)) >> 16); }
        CVT(0, f0.x) CVT(1, f0.y) CVT(2, f0.z) CVT(3, f0.w)
        CVT(4, f1.x) CVT(5, f1.y) CVT(6, f1.z) CVT(7, f1.w)
#undef CVT
        Xh[s] = th;
    }
    xs_part += __shfl_xor(xs_part, 16, 64);
    xs_part += __shfl_xor(xs_part, 32, 64);
    if (h == 0) xs_sh[wv][r] = xs_part;

    // stage tile ct into buf: 16 segs of (64 lanes x 16B). Dest linear
    // (wave-uniform base + lane*16B); source pre-swizzled so that the
    // swizzled READ (byte ^= (row&7)<<4) recovers linear columns.
#define STAGE(CT, BUF) { \
        for (int sg = wv; sg < 16; sg += 4) { \
            int hl = sg >> 3, s8 = sg & 7; \
            int u = (s8 << 6) + l; \
            int row_ = u >> 5, off16 = u & 31; \
            int colsh = (off16 << 3) ^ ((row_ & 7) << 3); \
            const unsigned short* gsrc = (hl ? el : eh) \
                + (size_t)((CT) * 16 + row_) * DD + colsh; \
            __builtin_amdgcn_global_load_lds( \
                (const __attribute__((address_space(1))) void*)gsrc, \
                (__attribute__((address_space(3))) void*)&et[BUF][hl][s8 << 9], \
                16, 0, 0); \
        } }

    // 8-slab MFMA tile body from LDS, 2 independent acc chains (Xh*Eh, Xh*El)
#define TILE_DOT(BUF, A0, A1) { \
        const unsigned short* bh_ = &et[BUF][0][rowoff]; \
        const unsigned short* bl_ = &et[BUF][1][rowoff]; \
        _Pragma("unroll") \
        for (int s = 0; s < 8; ++s) { \
            int colsh = ((h << 3) + (s << 5)) ^ sw3; \
            bf16x8 Eh_ = *(const bf16x8*)&bh_[colsh]; \
            bf16x8 El_ = *(const bf16x8*)&bl_[colsh]; \
            A0 = __builtin_amdgcn_mfma_f32_16x16x32_bf16(Xh[s], Eh_, A0, 0, 0, 0); \
            A1 = __builtin_amdgcn_mfma_f32_16x16x32_bf16(Xh[s], El_, A1, 0, 0, 0); \
        } }

    STAGE(0, 0)
    float xs4[4], sqx4[4];

    // ---- single pass: argmin + sum-exp + z-storage (fp16 pairs, 50 VGPR)
    float mind[4] = {1e30f, 1e30f, 1e30f, 1e30f};
    int   marg[4] = {0, 0, 0, 0};
    float se[4]   = {0.f, 0.f, 0.f, 0.f};
    __half2 zst[25][2];
    #pragma unroll
    for (int ct = 0; ct < 25; ++ct) {
        __syncthreads();
        if (ct == 0) {
            #pragma unroll
            for (int q = 0; q < 4; ++q) {
                xs4[q]  = xs_sh[wv][4 * h + q];
                sqx4[q] = sqrtf(xs4[q]);
            }
        }
        if (ct < 24) STAGE(ct + 1, (ct + 1) & 1)
        f32x4 a0 = {0.f,0.f,0.f,0.f}, a1 = {0.f,0.f,0.f,0.f};
        TILE_DOT(ct & 1, a0, a1)
        const int c = ct * 16 + r;
        const float ec = esq_g[c];
        float z4[4];
        #pragma unroll
        for (int q = 0; q < 4; ++q) {
            float dot = a0[q] + a1[q];
            float dist = fmaf(-2.f, dot, xs4[q] + ec);
            float z = sqx4[q] - sqrtf(fmaxf(dist, 0.f));
            z4[q] = z;
            se[q] += __expf(z);
            if (dist < mind[q]) { mind[q] = dist; marg[q] = c; }
        }
        zst[ct][0] = __floats2half2_rn(z4[0], z4[1]);
        zst[ct][1] = __floats2half2_rn(z4[2], z4[3]);
    }
    // reduce across the 16 code-lanes of this h-group
    #pragma unroll
    for (int q = 0; q < 4; ++q) {
        float bd = mind[q]; int bi = marg[q]; float s_ = se[q];
        #pragma unroll
        for (int off = 1; off < 16; off <<= 1) {
            float od = __shfl_xor(bd, off, 64);
            int   oi = __shfl_xor(bi, off, 64);
            s_ += __shfl_xor(s_, off, 64);
            if (od < bd || (od == bd && oi < bi)) { bd = od; bi = oi; }
        }
        se[q] = 1.f / s_;           // inverse for the finish pass
        if (r == 0) {
            int n = tok0 + 4 * h + q;
            idxws[mod * NTOK + n] = bi;
            atomicAdd(&rowcnt[(mod * BB + b) * MM + bi], 1);
        }
    }

    // ---- finish: pH from stored z (no staging, no MFMA)
    #pragma unroll
    for (int ct = 0; ct < 25; ++ct) {
        const int c = ct * 16 + r;
        float val = __expf(__low2float(zst[ct][0]))  * se[0]
                  + __expf(__high2float(zst[ct][0])) * se[1]
                  + __expf(__low2float(zst[ct][1]))  * se[2]
                  + __expf(__high2float(zst[ct][1])) * se[3];
        val += __shfl_xor(val, 16, 64);
        val += __shfl_xor(val, 32, 64);
        if (h == 0) pH_w[wv * MM + c] = val;
    }
#undef TILE_DOT
#undef STAGE

    __syncthreads();
    for (int m = tid; m < MM; m += 256) {
        float s = pH_w[m] + pH_w[MM + m] + pH_w[2 * MM + m] + pH_w[3 * MM + m];
        atomicAdd(&pH_g[(size_t)(mod * BB + b) * MM + m], s);
    }
}

// ---------------------------------------------------------------- quantized outputs + error sums
// R15 (VERIFIED): nontemporal out-stream (no L2 thrash) + 4 tok/wave.
__global__ void k_err(const float* __restrict__ a, const float* __restrict__ v,
                      const float* __restrict__ emb, const int* __restrict__ idxws,
                      float* __restrict__ out, float* __restrict__ err) {
    const int mod = blockIdx.y;
    const int tid = threadIdx.x;
    const int wv  = tid >> 6;
    const int d4  = (tid & 63) << 2;
    const float* x = (mod == 0) ? a : v;
    float* outm = out + (size_t)mod * NTOK * DD;

    float eo = 0.f, ec = 0.f;
    #pragma unroll
    for (int it = 0; it < 4; ++it) {
        const int n = blockIdx.x * 16 + (it << 2) + wv;
        const int ia = idxws[n];
        const int iv = idxws[NTOK + n];
        const int own = (mod == 0) ? ia : iv;
        const int oth = (mod == 0) ? iv : ia;

        float4 xv = *(const float4*)(x + (size_t)n * DD + d4);
        float4 qo = *(const float4*)(emb + (size_t)own * DD + d4);
        float4 qc = *(const float4*)(emb + (size_t)oth * DD + d4);
        f32x4 qv = {qo.x, qo.y, qo.z, qo.w};
        __builtin_nontemporal_store(qv, (f32x4*)(outm + (size_t)n * DD + d4));

        { float dx = xv.x - qo.x, dy = xv.y - qo.y, dz = xv.z - qo.z, dw = xv.w - qo.w;
          eo += dx * dx + dy * dy + dz * dz + dw * dw; }
        { float dx = xv.x - qc.x, dy = xv.y - qc.y, dz = xv.z - qc.z, dw = xv.w - qc.w;
          ec += dx * dx + dy * dy + dz * dz + dw * dw; }
    }

    #pragma unroll
    for (int off = 1; off < 64; off <<= 1) {
        eo += __shfl_xor(eo, off, 64);
        ec += __shfl_xor(ec, off, 64);
    }
    __shared__ float ro[4], rc[4];
    if ((tid & 63) == 0) { ro[wv] = eo; rc[wv] = ec; }
    __syncthreads();
    if (tid == 0) {
        int slot = blockIdx.x & 63;    // 64-way slotted: contention /64
        atomicAdd(&err[(mod * 2 + 0) * 64 + slot], ro[0] + ro[1] + ro[2] + ro[3]);
        atomicAdd(&err[(mod * 2 + 1) * 64 + slot], rc[0] + rc[1] + rc[2] + rc[3]);
    }
}

// ---------------------------------------------------------------- normalize pH, logs
__global__ void k2_norm(float* __restrict__ pH, float* __restrict__ Lg) {
    int i = blockIdx.x * 256 + threadIdx.x;
    if (i < 2 * BB * MM) {
        float p = pH[i] * (1.f / TT);
        pH[i] = p;
        Lg[i] = logf(p + 1e-10f);
    }
}

// ---------------------------------------------------------------- per-row mode
__global__ void k3_mode(const int* __restrict__ rowcnt, int* __restrict__ modes) {
    int r = blockIdx.x, lane = threadIdx.x;
    const int* cnt = rowcnt + r * MM;
    int bc = -1, bi = 0x7fffffff;
    for (int m = lane; m < MM; m += 64) {
        int c = cnt[m];
        if (c > bc) { bc = c; bi = m; }
    }
    #pragma unroll
    for (int off = 1; off < 64; off <<= 1) {
        int oc = __shfl_xor(bc, off, 64);
        int oi = __shfl_xor(bi, off, 64);
        if (oc > bc || (oc == bc && oi < bi)) { bc = oc; bi = oi; }
    }
    if (lane == 0) modes[r] = bi;
}

// ---------------------------------------------------------------- Scode (64x64, K=400, x2 terms)
__global__ void k4_scode(const float* __restrict__ pH, const float* __restrict__ Lg,
                         float* __restrict__ Sc) {
    int i = blockIdx.x;
    int tid = threadIdx.x, lane = tid & 63, wv = tid >> 6;
    const float* aPH = pH + (size_t)i * MM;
    const float* vPH = pH + (size_t)(BB + i) * MM;
    for (int jj = 0; jj < 16; ++jj) {
        int j = wv * 16 + jj;
        const float* Lv = Lg + (size_t)(BB + j) * MM;
        const float* La = Lg + (size_t)j * MM;
        float s = 0.f;
        for (int m = lane; m < MM; m += 64)
            s += aPH[m] * Lv[m] + vPH[m] * La[m];
        #pragma unroll
        for (int off = 1; off < 64; off <<= 1) s += __shfl_xor(s, off, 64);
        if (lane == 0) Sc[i * BB + j] = s;
    }
}

// ---------------------------------------------------------------- final scalars
__global__ void k5_final(const float* __restrict__ Sc, const int* __restrict__ rowcnt,
                         const float* __restrict__ err, const int* __restrict__ modes,
                         float* __restrict__ outs) {
    __shared__ float red[4];
    __shared__ float mx_sh;
    int tid = threadIdx.x;
    int lane = tid & 63, wv = tid >> 6;

    float lmin = 1e30f;
    for (int i = tid; i < BB * BB; i += 256) lmin = fminf(lmin, Sc[i]);
    #pragma unroll
    for (int off = 1; off < 64; off <<= 1) lmin = fminf(lmin, __shfl_xor(lmin, off, 64));
    if (lane == 0) red[wv] = lmin;
    __syncthreads();
    if (tid == 0) mx_sh = -fminf(fminf(red[0], red[1]), fminf(red[2], red[3]));
    __syncthreads();
    float Mx = mx_sh;

    if (wv == 0) {
        int i = lane;
        float rs = 0.f;
        for (int j = 0; j < BB; ++j) rs += __expf(Sc[i * BB + j] + Mx);
        float dg = __expf(Sc[i * BB + i] + Mx);
        float term = logf(dg / (rs + 1e-5f));
        #pragma unroll
        for (int off = 1; off < 64; off <<= 1) term += __shfl_xor(term, off, 64);
        if (lane == 0) outs[4] = 0.5f * (-(term / (float)BB));
    } else if (wv == 1 || wv == 2) {
        int mod = wv - 1;
        float s = 0.f;
        for (int m = lane; m < MM; m += 64) {
            int c = 0;
            for (int bb = 0; bb < BB; ++bb)
                c += rowcnt[(size_t)(mod * BB + bb) * MM + m];
            float p = (float)c * (1.f / (float)NTOK);
            s += p * logf(p + 1e-10f);
        }
        #pragma unroll
        for (int off = 1; off < 64; off <<= 1) s += __shfl_xor(s, off, 64);
        if (lane == 0) outs[2 + mod] = __expf(-s);
    } else {
        // error sums from 64 slots each
        float e0 = err[0 * 64 + lane], e1 = err[1 * 64 + lane];
        float e2 = err[2 * 64 + lane], e3 = err[3 * 64 + lane];
        int eq = (modes[lane] == modes[BB + lane]) ? 1 : 0;
        #pragma unroll
        for (int off = 1; off < 64; off <<= 1) {
            e0 += __shfl_xor(e0, off, 64);
            e1 += __shfl_xor(e1, off, 64);
            e2 += __shfl_xor(e2, off, 64);
            e3 += __shfl_xor(e3, off, 64);
            eq += __shfl_xor(eq, off, 64);
        }
        if (lane == 0) {
            outs[5] = (float)eq;
            const float inv = 1.f / (float)((size_t)NTOK * DD);
            float a_e = e0 * inv, av_e = e1 * inv;
            float v_e = e2 * inv, va_e = e3 * inv;
            outs[0] = 0.5f * a_e + 0.25f * av_e;
            outs[1] = 0.5f * v_e + 0.25f * va_e;
        }
    }
}

// ----------------------------------------------------------------
extern "C" void kernel_launch(void* const* d_in, const int* in_sizes, int n_in,
                              void* d_out, int out_size, void* d_ws, size_t ws_size,
                              hipStream_t stream) {
    (void)in_sizes; (void)n_in; (void)out_size; (void)ws_size;
    const float* a   = (const float*)d_in[0];
    const float* v   = (const float*)d_in[1];
    const float* emb = (const float*)d_in[2];
    float* out = (float*)d_out;
    char* ws = (char*)d_ws;

    float* pH_g   = (float*)(ws + WS_PH);
    int*   rowcnt = (int*)(ws + WS_ROWCNT);
    float* err    = (float*)(ws + WS_ERR);
    int*   idxws  = (int*)(ws + WS_IDX);
    float* esq    = (float*)(ws + WS_ESQ);
    float* Lg     = (float*)(ws + WS_LG);
    float* Sc     = (float*)(ws + WS_SC);
    int*   modes  = (int*)(ws + WS_MODE);
    unsigned short* eh = (unsigned short*)(ws + WS_EH);
    unsigned short* el = (unsigned short*)(ws + WS_EL);

    hipMemsetAsync(d_ws, 0, WS_ZERO_BYTES, stream);
    k_esq<<<MM, 64, 0, stream>>>(emb, esq, eh, el);
    k1_mfma<<<1024, 256, 0, stream>>>(a, v, eh, el, esq, pH_g, rowcnt, idxws);
    k_err<<<dim3(2048, 2), 256, 0, stream>>>(a, v, emb, idxws, out, err);
    k2_norm<<<200, 256, 0, stream>>>(pH_g, Lg);
    k3_mode<<<128, 64, 0, stream>>>(rowcnt, modes);
    k4_scode<<<BB, 256, 0, stream>>>(pH_g, Lg, Sc);
    k5_final<<<1, 256, 0, stream>>>(Sc, rowcnt, err, modes, out + (size_t)2 * NTOK * DD);
}